// Round 18
// baseline (321.193 us; speedup 1.0000x reference)
//
#include <hip/hip_runtime.h>
#include <hip/hip_bf16.h>

// Problem constants (from setup_inputs: x = [2, 1024, 64] fp32)
constexpr int BB = 2;
constexpr int N  = 1024;
constexpr int C  = 64;
constexpr int S  = N * N;          // 1048576 = 2^20
constexpr int KSEL = S / 6;        // 174762 entries set to 1 per batch
constexpr int EQCAP   = 1 << 17;   // candidate capacity per batch
constexpr int NSELBLK = 256;       // select grid == #CUs -> co-resident
constexpr unsigned int HEXIT = 16384;  // stage-A early-exit bucket threshold

typedef double d4 __attribute__((ext_vector_type(4)));

// Order-preserving uint64 mapping of fp64 (monotone: a<b <=> key(a)<key(b))
__device__ __forceinline__ unsigned long long d2key(double d) {
    unsigned long long u = (unsigned long long)__double_as_longlong(d);
    return (u & 0x8000000000000000ULL) ? ~u : (u | 0x8000000000000000ULL);
}

__device__ __forceinline__ unsigned int aload(const unsigned int* p) {
    return __hip_atomic_load(p, __ATOMIC_RELAXED, __HIP_MEMORY_SCOPE_AGENT);
}
__device__ __forceinline__ unsigned long long aload64(const unsigned long long* p) {
    return __hip_atomic_load(p, __ATOMIC_RELAXED, __HIP_MEMORY_SCOPE_AGENT);
}
__device__ __forceinline__ void astore64(unsigned long long* p, unsigned long long v) {
    (void)__hip_atomic_exchange(p, v, __ATOMIC_RELAXED, __HIP_MEMORY_SCOPE_AGENT);
}

// XCD-aware tile remap for the 32x16 tile grid (512 blocks/slice, 8 XCDs x 64).
__device__ __forceinline__ void xcd_tile(int& i0, int& j0) {
    int lin = (int)blockIdx.x + 32 * (int)blockIdx.y;
    int xcd = lin & 7, idx = lin >> 3;            // idx 0..63
    int nby = (xcd >> 1) * 4 + (idx >> 4);        // 0..15 (64-row tiles)
    int nbx = (xcd & 1) * 16 + (idx & 15);        // 0..31 (32-col tiles)
    i0 = nby * 64; j0 = nbx * 32;
}

// Parallel 256-bucket top-down threshold pick (256-thread blocks only).
// Also publishes the picked bucket's count -> *s_hc.
__device__ __forceinline__ void pick256(unsigned int c, unsigned int kneed,
                                        int t, unsigned int* wsum,
                                        unsigned int* s_bk, unsigned int* s_ca,
                                        unsigned int* s_hc) {
    int lane = t & 63, wv = t >> 6;
    unsigned int ws = c;
#pragma unroll
    for (int off = 1; off < 64; off <<= 1) {
        unsigned int o = __shfl_down(ws, off);
        if (lane + off < 64) ws += o;
    }
    if (lane == 0) wsum[wv] = ws;   // wave total (suffix at lane 0)
    __syncthreads();
    unsigned int add = 0;
#pragma unroll
    for (int w2 = 1; w2 < 4; ++w2) if (w2 > wv) add += wsum[w2];
    unsigned int S_t = ws + add, S_nx = S_t - c;
    if (S_t >= kneed && S_nx < kneed) {
        *s_bk = (unsigned int)t; *s_ca = S_nx; *s_hc = c;
    }
    __syncthreads();
}

// ---------------------------------------------------------------------------
// K1: pairwise adjacencies with fused per-row stats. 64x64 tile (512 wgs).
__global__ __launch_bounds__(256) void k_pairwise(const float* __restrict__ x,
                                                  double* __restrict__ E,
                                                  double* __restrict__ Ch,
                                                  double* __restrict__ Cc) {
    int b  = blockIdx.z;
    int i0 = blockIdx.y * 64;
    int j0 = blockIdx.x * 64;
    __shared__ double xi[64][65];
    __shared__ double xj[64][65];
    __shared__ double mi[64], ri_[64], si[64];
    __shared__ double mj[64], rj_[64], sj[64];

    int t  = threadIdx.x;
    int r  = t >> 2;
    int cb = (t & 3) * 16;
    const float* xb = x + (size_t)b * N * C;
    {
        const float4* pi = (const float4*)(xb + (size_t)(i0 + r) * C + cb);
        const float4* pj = (const float4*)(xb + (size_t)(j0 + r) * C + cb);
#pragma unroll
        for (int m4 = 0; m4 < 4; ++m4) {
            float4 fi = pi[m4], fj = pj[m4];
            xi[r][cb + 4 * m4 + 0] = (double)fi.x; xi[r][cb + 4 * m4 + 1] = (double)fi.y;
            xi[r][cb + 4 * m4 + 2] = (double)fi.z; xi[r][cb + 4 * m4 + 3] = (double)fi.w;
            xj[r][cb + 4 * m4 + 0] = (double)fj.x; xj[r][cb + 4 * m4 + 1] = (double)fj.y;
            xj[r][cb + 4 * m4 + 2] = (double)fj.z; xj[r][cb + 4 * m4 + 3] = (double)fj.w;
        }
    }
    __syncthreads();

    if (t < 128) {
        int row = t & 63;
        const double (*xs)[65] = (t < 64) ? xi : xj;
        double sum = 0.0, rr = 0.0;
#pragma unroll 8
        for (int c = 0; c < 64; ++c) { double v = xs[row][c]; sum += v; rr = fma(v, v, rr); }
        double m = sum / 64.0;
        double q = 0.0;
#pragma unroll 8
        for (int c = 0; c < 64; ++c) { double w = xs[row][c] - m; q = fma(w, w, q); }
        double sv = 1.0 / sqrt(q);
        if (t < 64) { mi[row] = m; ri_[row] = rr; si[row] = sv; }
        else        { mj[row] = m; rj_[row] = rr; sj[row] = sv; }
    }
    __syncthreads();

    int ty = t >> 4, tx = t & 15;
    double adot[4][4] = {};
    double amax[4][4] = {};
#pragma unroll 8
    for (int c = 0; c < 64; ++c) {
        double ai[4], aj[4];
#pragma unroll
        for (int p = 0; p < 4; ++p) ai[p] = xi[ty + 16 * p][c];
#pragma unroll
        for (int q = 0; q < 4; ++q) aj[q] = xj[tx + 16 * q][c];
#pragma unroll
        for (int p = 0; p < 4; ++p)
#pragma unroll
            for (int q = 0; q < 4; ++q) {
                double d = ai[p] - aj[q];
                amax[p][q] = fmax(amax[p][q], fabs(d));
                adot[p][q] = fma(ai[p], aj[q], adot[p][q]);
            }
    }

#pragma unroll
    for (int p = 0; p < 4; ++p) {
        int li = ty + 16 * p;
        int ii = i0 + li;
        double rri = ri_[li], mmi = mi[li], ssi = si[li];
#pragma unroll
        for (int q = 0; q < 4; ++q) {
            int lj = tx + 16 * q;
            int jj = j0 + lj;
            double dot = adot[p][q];
            double d2  = rri + rj_[lj] - 2.0 * dot;
            double e   = (ii == jj) ? 0.0 : sqrt(fmax(d2, 0.0));
            double cc  = (dot - 64.0 * mmi * mj[lj]) * ssi * sj[lj];
            cc = fmin(1.0, fmax(-1.0, cc));
            size_t idx = (size_t)b * S + (size_t)ii * N + jj;
            E[idx]  = e;
            Ch[idx] = amax[p][q];
            Cc[idx] = cc;
        }
    }
}

// ---------------------------------------------------------------------------
// K2: C = scale * A * B^T (fp64, MFMA). 64x32 tile, 256 threads, 4 waves x
// (16x32); 1024 wgs -> 4 blocks/CU (verified 282.6us round). BK=16 dbuf.
__global__ __launch_bounds__(256, 4) void k_gemm_nt(const double* __restrict__ A,
                                                    const double* __restrict__ Bm,
                                                    double* __restrict__ Cm,
                                                    double scale,
                                                    unsigned int* __restrict__ bar,
                                                    unsigned int* __restrict__ ghist,
                                                    unsigned int* __restrict__ eqcnt,
                                                    unsigned long long* __restrict__ pubR) {
    if (blockIdx.x == 0 && blockIdx.y == 0 && blockIdx.z == 0) {
        int tt = threadIdx.x;
        for (int i = tt; i < 512; i += 256) bar[i] = 0u;
        for (int i = tt; i < 4 * 2 * 16 * 256; i += 256) ghist[i] = 0u;
        if (tt < 32) eqcnt[tt] = 0u;
        if (tt < 16) { pubR[tt] = 0ULL; }
    }

    int b = blockIdx.z;
    const double* Ab = A  + (size_t)b * S;
    const double* Bb = Bm + (size_t)b * S;
    double*       Cb = Cm + (size_t)b * S;
    int i0, j0;
    xcd_tile(i0, j0);    // i0: 64-row base, j0: 32-col base

    __shared__ double At[2][64][17];
    __shared__ double Bt[2][32][17];

    int t    = threadIdx.x;
    int lane = t & 63;
    int w    = t >> 6;            // 0..3, rows [w*16, w*16+16)
    int wrr  = w * 16;
    int fm   = lane & 15;
    int fk   = lane >> 4;

    int sa_r = t >> 2, sa_c = (t & 3) * 4;   // A: 64 rows x 16 k, 4 dbl/thr
    int sb_r = t >> 3, sb_c = (t & 7) * 2;   // B: 32 j-rows x 16 k, 2 dbl/thr

    d4 acc0 = {0.0, 0.0, 0.0, 0.0};
    d4 acc1 = acc0;

    const double* ap = Ab + (size_t)(i0 + sa_r) * N + sa_c;
    const double* bp = Bb + (size_t)(j0 + sb_r) * N + sb_c;

    double pa[4], pb[2];
#pragma unroll
    for (int m = 0; m < 4; ++m) pa[m] = ap[m];
#pragma unroll
    for (int m = 0; m < 2; ++m) pb[m] = bp[m];
#pragma unroll
    for (int m = 0; m < 4; ++m) At[0][sa_r][sa_c + m] = pa[m];
#pragma unroll
    for (int m = 0; m < 2; ++m) Bt[0][sb_r][sb_c + m] = pb[m];
    __syncthreads();

    int cur = 0;
    for (int k0 = 0; k0 < N; k0 += 16) {
        bool has_next = (k0 + 16 < N);
        if (has_next) {
            ap += 16; bp += 16;
#pragma unroll
            for (int m = 0; m < 4; ++m) pa[m] = ap[m];
#pragma unroll
            for (int m = 0; m < 2; ++m) pb[m] = bp[m];
        }
#pragma unroll
        for (int kq = 0; kq < 4; ++kq) {
            int kk = kq * 4 + fk;
            double a0 = At[cur][wrr + fm][kk];
            double b0 = Bt[cur][fm][kk];
            double b1 = Bt[cur][16 + fm][kk];
            acc0 = __builtin_amdgcn_mfma_f64_16x16x4f64(a0, b0, acc0, 0, 0, 0);
            acc1 = __builtin_amdgcn_mfma_f64_16x16x4f64(a0, b1, acc1, 0, 0, 0);
        }
        if (has_next) {
            int nxt = cur ^ 1;
#pragma unroll
            for (int m = 0; m < 4; ++m) At[nxt][sa_r][sa_c + m] = pa[m];
#pragma unroll
            for (int m = 0; m < 2; ++m) Bt[nxt][sb_r][sb_c + m] = pb[m];
            __syncthreads();
            cur = nxt;
        }
    }
    int r0 = i0 + wrr + 4 * fk;
    int c0 = j0 + fm;
#pragma unroll
    for (int r = 0; r < 4; ++r) {
        Cb[(size_t)(r0 + r) * N + c0]      = acc0[r] * scale;
        Cb[(size_t)(r0 + r) * N + c0 + 16] = acc1[r] * scale;
    }
}

// ---------------------------------------------------------------------------
// K4: W = A * B (fp64, MFMA) + key32 epilogue + pass-0 radix histogram.
__global__ __launch_bounds__(256, 4) void k_gemm_nn(const double* __restrict__ A,
                                                    const double* __restrict__ Bm,
                                                    double* __restrict__ Wm,
                                                    unsigned int* __restrict__ kq_out,
                                                    unsigned int* __restrict__ ghist) {
    int b = blockIdx.z;
    const double* Ab = A  + (size_t)b * S;
    const double* Bb = Bm + (size_t)b * S;
    double*       Wb = Wm + (size_t)b * S;
    unsigned int* kb = kq_out + (size_t)b * S;
    int i0, j0;
    xcd_tile(i0, j0);

    __shared__ double At[2][64][17];
    __shared__ double Bt[2][16][33];
    __shared__ int bh[256];

    int t    = threadIdx.x;
    int lane = t & 63;
    int w    = t >> 6;            // 0..3
    int wrr  = w * 16;
    int fm   = lane & 15;
    int fk   = lane >> 4;

    int sa_r = t >> 2, sa_c = (t & 3) * 4;    // A: 64 rows x 16 k
    int sb_r = t >> 4, sb_c = (t & 15) * 2;   // B: 16 k-rows x 32 cols

    d4 acc0 = {0.0, 0.0, 0.0, 0.0};
    d4 acc1 = acc0;

    const double* ap = Ab + (size_t)(i0 + sa_r) * N + sa_c;
    const double* bp = Bb + (size_t)sb_r * N + j0 + sb_c;

    double pa[4], pb[2];
#pragma unroll
    for (int m = 0; m < 4; ++m) pa[m] = ap[m];
#pragma unroll
    for (int m = 0; m < 2; ++m) pb[m] = bp[m];
#pragma unroll
    for (int m = 0; m < 4; ++m) At[0][sa_r][sa_c + m] = pa[m];
#pragma unroll
    for (int m = 0; m < 2; ++m) Bt[0][sb_r][sb_c + m] = pb[m];
    __syncthreads();

    int cur = 0;
    for (int k0 = 0; k0 < N; k0 += 16) {
        bool has_next = (k0 + 16 < N);
        if (has_next) {
            ap += 16; bp += (size_t)16 * N;
#pragma unroll
            for (int m = 0; m < 4; ++m) pa[m] = ap[m];
#pragma unroll
            for (int m = 0; m < 2; ++m) pb[m] = bp[m];
        }
#pragma unroll
        for (int kq = 0; kq < 4; ++kq) {
            int kk = kq * 4 + fk;
            double a0 = At[cur][wrr + fm][kk];
            double b0 = Bt[cur][kk][fm];
            double b1 = Bt[cur][kk][16 + fm];
            acc0 = __builtin_amdgcn_mfma_f64_16x16x4f64(a0, b0, acc0, 0, 0, 0);
            acc1 = __builtin_amdgcn_mfma_f64_16x16x4f64(a0, b1, acc1, 0, 0, 0);
        }
        if (has_next) {
            int nxt = cur ^ 1;
#pragma unroll
            for (int m = 0; m < 4; ++m) At[nxt][sa_r][sa_c + m] = pa[m];
#pragma unroll
            for (int m = 0; m < 2; ++m) Bt[nxt][sb_r][sb_c + m] = pb[m];
            __syncthreads();
            cur = nxt;
        }
    }
    int r0 = i0 + wrr + 4 * fk;
    int c0 = j0 + fm;

    unsigned int kreg[8];
#pragma unroll
    for (int r = 0; r < 4; ++r) {
        double w00 = acc0[r], w01 = acc1[r];
        size_t i00 = (size_t)(r0 + r) * N + c0;
        size_t i01 = (size_t)(r0 + r) * N + c0 + 16;
        unsigned int k00 = (unsigned int)(d2key(w00) >> 32);
        unsigned int k01 = (unsigned int)(d2key(w01) >> 32);
        Wb[i00] = w00; kb[i00] = k00;
        Wb[i01] = w01; kb[i01] = k01;
        kreg[2 * r + 0] = k00; kreg[2 * r + 1] = k01;
    }

    // pass-0 (top-byte) histogram of this block's 2048 outputs
    bh[t] = 0;
    __syncthreads();
#pragma unroll
    for (int m = 0; m < 8; ++m) atomicAdd(&bh[kreg[m] >> 24], 1);
    __syncthreads();
    if (bh[t] != 0)
        __hip_atomic_fetch_add(&ghist[((0 * 2 + b) * 16 + (blockIdx.x & 15)) * 256 + t],
                               (unsigned int)bh[t], __ATOMIC_RELAXED,
                               __HIP_MEMORY_SCOPE_AGENT);
}

// ---------------------------------------------------------------------------
// K3: fp64 row softmax. Wave per row, shuffle-only; 512 wgs.
__global__ __launch_bounds__(256) void k_softmax(double* __restrict__ L) {
    int row = (blockIdx.x << 2) + (threadIdx.x >> 6);
    int ln  = threadIdx.x & 63;
    double* p = L + (size_t)row * N;

    double v[16];
#pragma unroll
    for (int q = 0; q < 16; ++q) v[q] = p[ln + 64 * q];

    double mx = v[0];
#pragma unroll
    for (int q = 1; q < 16; ++q) mx = fmax(mx, v[q]);
#pragma unroll
    for (int off = 32; off >= 1; off >>= 1) mx = fmax(mx, __shfl_xor(mx, off));

    double s = 0.0;
#pragma unroll
    for (int q = 0; q < 16; ++q) { v[q] = exp(v[q] - mx); s += v[q]; }
#pragma unroll
    for (int off = 32; off >= 1; off >>= 1) s += __shfl_xor(s, off);

    double inv = 1.0 / s;
#pragma unroll
    for (int q = 0; q < 16; ++q) p[ln + 64 * q] = v[q] * inv;
}

// ---------------------------------------------------------------------------
// K5 v3: stage-A EARLY EXIT. Bucket counts shrink ~256x per radix pass, so
// once the boundary-bucket count h <= HEXIT, all blocks (which compute h
// redundantly -> uniform decision) stop scanning keys and collect candidates
// on the partial prefix. Collection stores the FULL 64-bit key (d2key(W[s]))
// in candA and the index in candB, so the leader refine radix-sorts the
// remaining (64-plen)+idx bits without further grid syncs. Typically skips
// 1-2 stage-A passes (key scan + arrival sync each).
__global__ __launch_bounds__(256) void k_select(const unsigned int* __restrict__ key32,
                                                const double* __restrict__ W,
                                                unsigned int* __restrict__ ghist,
                                                unsigned int* __restrict__ eqcnt,
                                                unsigned long long* __restrict__ candA,
                                                unsigned long long* __restrict__ candB,
                                                unsigned long long* __restrict__ pubR,
                                                unsigned int* __restrict__ bar,
                                                float* __restrict__ out) {
    int blk = blockIdx.x, t = threadIdx.x;
    int b  = blk >> 7;            // 128 blocks per batch
    int lb = blk & 127;
    int lane = t & 63, wv = t >> 6;
    bool leader = (lb == 0);

    __shared__ int lh[256];
    __shared__ int wtot[4];
    __shared__ unsigned int wsum[4];
    __shared__ unsigned int sbase, s_tot, s_bk, s_ca, s_hc;
    __shared__ unsigned long long s_pub, s_pub2;

    // XCD-aligned tile ownership: residue r8 = blk%8, two tiles per block.
    int r8 = blk & 7;
    int o  = lb >> 3;                       // 0..15
    int tf0 = r8 + 16 * o;
    int tf1 = tf0 + 8;
    int rr = t >> 2, c16 = (t & 3) * 16;
    int tb[2];
    tb[0] = ((tf0 >> 4) * 64 + rr) * N + (tf0 & 15) * 64 + c16;
    tb[1] = ((tf1 >> 4) * 64 + rr) * N + (tf1 & 15) * 64 + c16;

    const unsigned int* kb = key32 + (size_t)b * S;
    const double*       Wb = W     + (size_t)b * S;
    unsigned long long* cA = candA + (size_t)b * EQCAP;
    unsigned long long* cB = candB + (size_t)b * EQCAP;
    unsigned int* arr = bar + 64;   // arrival counters, 16-dword spacing

    unsigned int pref = 0, kneed = (unsigned int)KSEL;
    int plen = 8;

    // ---- stage A: radix passes with early exit (pass-0 hist from K4) ----
    for (int p = 0; p < 4; ++p) {
        int shift = 24 - 8 * p;
        if (p > 0) {
            lh[t] = 0;
            __syncthreads();
#pragma unroll
            for (int u = 0; u < 2; ++u)
#pragma unroll
                for (int m4 = 0; m4 < 4; ++m4) {
                    uint4 kv = *(const uint4*)(kb + tb[u] + 4 * m4);
                    unsigned int ks[4] = {kv.x, kv.y, kv.z, kv.w};
#pragma unroll
                    for (int c = 0; c < 4; ++c) {
                        bool match = (((unsigned long long)(ks[c] ^ pref)) >> (shift + 8)) == 0ULL;
                        if (match) atomicAdd(&lh[(ks[c] >> shift) & 255u], 1);
                    }
                }
            __syncthreads();
            if (lh[t] != 0)
                __hip_atomic_fetch_add(&ghist[((p * 2 + b) * 16 + (lb >> 3)) * 256 + t],
                                       (unsigned int)lh[t], __ATOMIC_RELAXED,
                                       __HIP_MEMORY_SCOPE_AGENT);
            asm volatile("s_waitcnt vmcnt(0)" ::: "memory");
            __syncthreads();
            if (t == 0) {
                unsigned int* slot = &arr[((p - 1) * 2 + b) * 16];
                __hip_atomic_fetch_add(slot, 1u, __ATOMIC_RELAXED,
                                       __HIP_MEMORY_SCOPE_AGENT);
                while (aload(slot) < 128u) __builtin_amdgcn_s_sleep(4);
            }
            __syncthreads();
        }
        unsigned int c = 0;
#pragma unroll
        for (int g = 0; g < 16; ++g)
            c += aload(&ghist[((p * 2 + b) * 16 + g) * 256 + t]);
        pick256(c, kneed, t, wsum, &s_bk, &s_ca, &s_hc);
        pref |= (s_bk << shift);
        kneed -= s_ca;
        plen = 8 * (p + 1);
        if (p == 3 || s_hc <= HEXIT) break;   // uniform: identical ghist sums
    }
    int rsh = 32 - plen;                      // 24 / 16 / 8 / 0
    unsigned int prefv = pref >> rsh;

    // ---- collect candidates (prefix match): full key64 + index ----
    unsigned long long lmask = (1ULL << lane) - 1ULL;
    {
        int wcnt = 0;
#pragma unroll
        for (int u = 0; u < 2; ++u)
#pragma unroll
            for (int m4 = 0; m4 < 4; ++m4) {
                uint4 kv = *(const uint4*)(kb + tb[u] + 4 * m4);
                unsigned int ks[4] = {kv.x, kv.y, kv.z, kv.w};
#pragma unroll
                for (int c = 0; c < 4; ++c) {
                    unsigned long long mb = __ballot(((ks[c] ^ pref) >> rsh) == 0);
                    wcnt += (int)__popcll(mb);
                }
            }
        if (lane == 0) wtot[wv] = wcnt;
        __syncthreads();
        if (t == 0) {
            int tot = wtot[0] + wtot[1] + wtot[2] + wtot[3];
            s_tot = (unsigned int)tot;
            sbase = (tot > 0)
                ? __hip_atomic_fetch_add(&eqcnt[b * 16], (unsigned int)tot,
                                         __ATOMIC_RELAXED, __HIP_MEMORY_SCOPE_AGENT)
                : 0u;
        }
        __syncthreads();
        unsigned int wb2 = sbase;
        for (int w2 = 0; w2 < wv; ++w2) wb2 += (unsigned int)wtot[w2];
#pragma unroll
        for (int u = 0; u < 2; ++u)
#pragma unroll
            for (int m4 = 0; m4 < 4; ++m4) {
                uint4 kv = *(const uint4*)(kb + tb[u] + 4 * m4);
                unsigned int ks[4] = {kv.x, kv.y, kv.z, kv.w};
#pragma unroll
                for (int c = 0; c < 4; ++c) {
                    bool m = ((ks[c] ^ pref) >> rsh) == 0;
                    unsigned long long mb = __ballot(m);
                    if (m) {
                        unsigned int pos = wb2 + (unsigned int)__popcll(mb & lmask);
                        if (pos < (unsigned int)EQCAP) {
                            int s = tb[u] + 4 * m4 + c;
                            astore64(&cA[pos], d2key(Wb[s]));
                            astore64(&cB[pos], (unsigned long long)(unsigned int)s);
                        }
                    }
                    wb2 += (unsigned int)__popcll(mb);
                }
            }
    }
    asm volatile("s_waitcnt vmcnt(0)" ::: "memory");
    __syncthreads();
    if (t == 0)
        __hip_atomic_fetch_add(&arr[(6 + b) * 16], 1u,
                               __ATOMIC_RELAXED, __HIP_MEMORY_SCOPE_AGENT);
    unsigned int tot = s_tot;

    // ---- M1: provisional mask (bucket members -> 0), overlaps refine ----
    float4* ob = (float4*)(out + (size_t)b * S);
#pragma unroll
    for (int u = 0; u < 2; ++u)
#pragma unroll
        for (int m4 = 0; m4 < 4; ++m4) {
            uint4 kv = *(const uint4*)(kb + tb[u] + 4 * m4);
            unsigned int ks[4] = {kv.x, kv.y, kv.z, kv.w};
            float4 ov;
            ov.x = ((ks[0] >> rsh) > prefv) ? 1.0f : 0.0f;
            ov.y = ((ks[1] >> rsh) > prefv) ? 1.0f : 0.0f;
            ov.z = ((ks[2] >> rsh) > prefv) ? 1.0f : 0.0f;
            ov.w = ((ks[3] >> rsh) > prefv) ? 1.0f : 0.0f;
            ob[(tb[u] >> 2) + m4] = ov;
        }

    // ---- refine (leader block per batch): remaining key64 bits + idx ----
    if (leader) {
        if (t == 0)
            while (aload(&arr[(6 + b) * 16]) < 128u) __builtin_amdgcn_s_sleep(4);
        __syncthreads();
        unsigned int cnt = aload(&eqcnt[b * 16]);
        if (cnt > (unsigned int)EQCAP) cnt = EQCAP;
        unsigned long long rpref = ((unsigned long long)pref) << 32;
        unsigned int rkneed = kneed;
        for (int shift = 24 + rsh; shift >= 0; shift -= 8) {   // 64-plen-8 .. 0
            lh[t] = 0;
            __syncthreads();
            for (unsigned int e = t; e < cnt; e += 256) {
                unsigned long long k64 = aload64(&cA[e]);
                if (((k64 ^ rpref) >> (shift + 8)) == 0ULL)
                    atomicAdd(&lh[(unsigned int)((k64 >> shift) & 255ULL)], 1);
            }
            __syncthreads();
            pick256((unsigned int)lh[t], rkneed, t, wsum, &s_bk, &s_ca, &s_hc);
            rpref |= ((unsigned long long)s_bk) << shift;
            rkneed -= s_ca;
        }
        unsigned long long TL64 = rpref;
        unsigned int ipref = 0;
        for (int shift = 16; shift >= 0; shift -= 8) {
            lh[t] = 0;
            __syncthreads();
            for (unsigned int e = t; e < cnt; e += 256) {
                unsigned long long k64 = aload64(&cA[e]);
                if (k64 != TL64) continue;
                unsigned int idx = (unsigned int)aload64(&cB[e]);
                if ((((unsigned long long)(idx ^ ipref)) >> (shift + 8)) == 0ULL)
                    atomicAdd(&lh[(idx >> shift) & 255u], 1);
            }
            __syncthreads();
            pick256((unsigned int)lh[t], rkneed, t, wsum, &s_bk, &s_ca, &s_hc);
            ipref |= (s_bk << shift);
            rkneed -= s_ca;
        }
        if (t == 0) {
            astore64(&pubR[b * 8 + 1], (1ULL << 56) | (TL64 & 0xFFFFFFFFULL));
            astore64(&pubR[b * 8],
                     (1ULL << 56) | (((unsigned long long)ipref) << 32) | (TL64 >> 32));
        }
    } else if (tot == 0) {
        return;   // mask fully final for this block
    }
    if (tot == 0) return;   // leader with no local bucket members: done

    // ---- bucket holders: poll refine publish (2 tagged words), fix up ----
    if (t == 0) {
        unsigned long long v0, v1;
        for (;;) {
            v0 = aload64(&pubR[b * 8]);
            v1 = aload64(&pubR[b * 8 + 1]);
            if ((v0 >> 56) == 1ULL && (v1 >> 56) == 1ULL) break;
            __builtin_amdgcn_s_sleep(4);
        }
        s_pub = v0; s_pub2 = v1;
    }
    __syncthreads();
    unsigned long long TL64 = ((s_pub & 0xFFFFFFFFULL) << 32) | (s_pub2 & 0xFFFFFFFFULL);
    unsigned int sCut = (unsigned int)((s_pub >> 32) & 0xFFFFFULL);

    asm volatile("s_waitcnt vmcnt(0)" ::: "memory");   // M1 stores drained
    float* of = out + (size_t)b * S;
#pragma unroll
    for (int u = 0; u < 2; ++u)
#pragma unroll
        for (int m4 = 0; m4 < 4; ++m4) {
            uint4 kv = *(const uint4*)(kb + tb[u] + 4 * m4);
            unsigned int ks[4] = {kv.x, kv.y, kv.z, kv.w};
#pragma unroll
            for (int c = 0; c < 4; ++c) {
                if (((ks[c] ^ pref) >> rsh) == 0) {
                    int s = tb[u] + 4 * m4 + c;
                    unsigned long long k64 = d2key(Wb[s]);
                    of[s] = (k64 > TL64 || (k64 == TL64 && (unsigned int)s >= sCut))
                                ? 1.0f : 0.0f;
                }
            }
        }
}

// ---------------------------------------------------------------------------
extern "C" void kernel_launch(void* const* d_in, const int* in_sizes, int n_in,
                              void* d_out, int out_size, void* d_ws, size_t ws_size,
                              hipStream_t stream) {
    const float* x = (const float*)d_in[0];
    float* out = (float*)d_out;

    char* ws = (char*)d_ws;
    size_t off = 0;
    auto alloc = [&](size_t bytes) -> void* {
        void* p = ws + off;
        off += (bytes + 255) & ~(size_t)255;
        return p;
    };

    double* E     = (double*)alloc((size_t)BB * S * sizeof(double));       // 16 MB
    double* Ch    = (double*)alloc((size_t)BB * S * sizeof(double));       // 16 MB
    double* Cc    = (double*)alloc((size_t)BB * S * sizeof(double));       // 16 MB
    double* L     = (double*)alloc((size_t)BB * S * sizeof(double));       // 16 MB
    unsigned int* key32 = (unsigned int*)alloc((size_t)BB * S * sizeof(unsigned int)); // 8 MB
    double* W     = E;  // E dead after gemm_nt -> reuse for weighted
    unsigned int* bar   = (unsigned int*)alloc(2048);
    unsigned int* ghist = (unsigned int*)alloc(4 * 2 * 16 * 256 * sizeof(unsigned int)); // 128 KB
    unsigned int* eqcnt = (unsigned int*)alloc(BB * 64);
    unsigned long long* candA =
        (unsigned long long*)alloc((size_t)BB * EQCAP * sizeof(unsigned long long));     // 2 MB
    unsigned long long* candB =
        (unsigned long long*)alloc((size_t)BB * EQCAP * sizeof(unsigned long long));     // 2 MB
    unsigned long long* pubR = (unsigned long long*)alloc(128);

    // 1) pairwise adjacencies (fused per-row stats)
    k_pairwise<<<dim3(N / 64, N / 64, BB), 256, 0, stream>>>(x, E, Ch, Cc);

    // 2) logits = (E @ Ch^T) * 1/8, 64x32 tiles (+ zeroes select scratch)
    k_gemm_nt<<<dim3(N / 32, N / 64, BB), 256, 0, stream>>>(E, Ch, L, 0.125,
                                                            bar, ghist, eqcnt, pubR);

    // 3) softmax rows
    k_softmax<<<512, 256, 0, stream>>>(L);

    // 4) weighted = attn @ Cc, 64x32 tiles + key32 epilogue + pass-0 histogram
    k_gemm_nn<<<dim3(N / 32, N / 64, BB), 256, 0, stream>>>(L, Cc, W, key32, ghist);

    // 5) fused selection v3 (stage-A early exit, key64 candidates)
    k_select<<<NSELBLK, 256, 0, stream>>>(key32, W, ghist, eqcnt, candA, candB,
                                          pubR, bar, out);
}

// Round 20
// 282.432 us; speedup vs baseline: 1.1372x; 1.1372x over previous
//
#include <hip/hip_runtime.h>
#include <hip/hip_bf16.h>

// Problem constants (from setup_inputs: x = [2, 1024, 64] fp32)
constexpr int BB = 2;
constexpr int N  = 1024;
constexpr int C  = 64;
constexpr int S  = N * N;          // 1048576 = 2^20
constexpr int KSEL = S / 6;        // 174762 entries set to 1 per batch
constexpr int EQCAP   = 1 << 17;   // exact-tie capacity per batch (~32x margin)
constexpr int NSELBLK = 256;       // select grid == #CUs -> co-resident

typedef double d4 __attribute__((ext_vector_type(4)));

// Order-preserving uint64 mapping of fp64 (monotone: a<b <=> key(a)<key(b))
__device__ __forceinline__ unsigned long long d2key(double d) {
    unsigned long long u = (unsigned long long)__double_as_longlong(d);
    return (u & 0x8000000000000000ULL) ? ~u : (u | 0x8000000000000000ULL);
}

__device__ __forceinline__ unsigned int aload(const unsigned int* p) {
    return __hip_atomic_load(p, __ATOMIC_RELAXED, __HIP_MEMORY_SCOPE_AGENT);
}
__device__ __forceinline__ unsigned long long aload64(const unsigned long long* p) {
    return __hip_atomic_load(p, __ATOMIC_RELAXED, __HIP_MEMORY_SCOPE_AGENT);
}
__device__ __forceinline__ void astore64(unsigned long long* p, unsigned long long v) {
    (void)__hip_atomic_exchange(p, v, __ATOMIC_RELAXED, __HIP_MEMORY_SCOPE_AGENT);
}

// XCD-aware tile remap for the 32x16 tile grid (512 blocks/slice, 8 XCDs x 64).
__device__ __forceinline__ void xcd_tile(int& i0, int& j0) {
    int lin = (int)blockIdx.x + 32 * (int)blockIdx.y;
    int xcd = lin & 7, idx = lin >> 3;            // idx 0..63
    int nby = (xcd >> 1) * 4 + (idx >> 4);        // 0..15 (64-row tiles)
    int nbx = (xcd & 1) * 16 + (idx & 15);        // 0..31 (32-col tiles)
    i0 = nby * 64; j0 = nbx * 32;
}

// Parallel 256-bucket top-down threshold pick (256-thread blocks only).
__device__ __forceinline__ void pick256(unsigned int c, unsigned int kneed,
                                        int t, unsigned int* wsum,
                                        unsigned int* s_bk, unsigned int* s_ca) {
    int lane = t & 63, wv = t >> 6;
    unsigned int ws = c;
#pragma unroll
    for (int off = 1; off < 64; off <<= 1) {
        unsigned int o = __shfl_down(ws, off);
        if (lane + off < 64) ws += o;
    }
    if (lane == 0) wsum[wv] = ws;   // wave total (suffix at lane 0)
    __syncthreads();
    unsigned int add = 0;
#pragma unroll
    for (int w2 = 1; w2 < 4; ++w2) if (w2 > wv) add += wsum[w2];
    unsigned int S_t = ws + add, S_nx = S_t - c;
    if (S_t >= kneed && S_nx < kneed) { *s_bk = (unsigned int)t; *s_ca = S_nx; }
    __syncthreads();
}

// ---------------------------------------------------------------------------
// K1: pairwise adjacencies with fused per-row stats. 64x64 tile (512 wgs).
__global__ __launch_bounds__(256) void k_pairwise(const float* __restrict__ x,
                                                  double* __restrict__ E,
                                                  double* __restrict__ Ch,
                                                  double* __restrict__ Cc) {
    int b  = blockIdx.z;
    int i0 = blockIdx.y * 64;
    int j0 = blockIdx.x * 64;
    __shared__ double xi[64][65];
    __shared__ double xj[64][65];
    __shared__ double mi[64], ri_[64], si[64];
    __shared__ double mj[64], rj_[64], sj[64];

    int t  = threadIdx.x;
    int r  = t >> 2;
    int cb = (t & 3) * 16;
    const float* xb = x + (size_t)b * N * C;
    {
        const float4* pi = (const float4*)(xb + (size_t)(i0 + r) * C + cb);
        const float4* pj = (const float4*)(xb + (size_t)(j0 + r) * C + cb);
#pragma unroll
        for (int m4 = 0; m4 < 4; ++m4) {
            float4 fi = pi[m4], fj = pj[m4];
            xi[r][cb + 4 * m4 + 0] = (double)fi.x; xi[r][cb + 4 * m4 + 1] = (double)fi.y;
            xi[r][cb + 4 * m4 + 2] = (double)fi.z; xi[r][cb + 4 * m4 + 3] = (double)fi.w;
            xj[r][cb + 4 * m4 + 0] = (double)fj.x; xj[r][cb + 4 * m4 + 1] = (double)fj.y;
            xj[r][cb + 4 * m4 + 2] = (double)fj.z; xj[r][cb + 4 * m4 + 3] = (double)fj.w;
        }
    }
    __syncthreads();

    if (t < 128) {
        int row = t & 63;
        const double (*xs)[65] = (t < 64) ? xi : xj;
        double sum = 0.0, rr = 0.0;
#pragma unroll 8
        for (int c = 0; c < 64; ++c) { double v = xs[row][c]; sum += v; rr = fma(v, v, rr); }
        double m = sum / 64.0;
        double q = 0.0;
#pragma unroll 8
        for (int c = 0; c < 64; ++c) { double w = xs[row][c] - m; q = fma(w, w, q); }
        double sv = 1.0 / sqrt(q);
        if (t < 64) { mi[row] = m; ri_[row] = rr; si[row] = sv; }
        else        { mj[row] = m; rj_[row] = rr; sj[row] = sv; }
    }
    __syncthreads();

    int ty = t >> 4, tx = t & 15;
    double adot[4][4] = {};
    double amax[4][4] = {};
#pragma unroll 8
    for (int c = 0; c < 64; ++c) {
        double ai[4], aj[4];
#pragma unroll
        for (int p = 0; p < 4; ++p) ai[p] = xi[ty + 16 * p][c];
#pragma unroll
        for (int q = 0; q < 4; ++q) aj[q] = xj[tx + 16 * q][c];
#pragma unroll
        for (int p = 0; p < 4; ++p)
#pragma unroll
            for (int q = 0; q < 4; ++q) {
                double d = ai[p] - aj[q];
                amax[p][q] = fmax(amax[p][q], fabs(d));
                adot[p][q] = fma(ai[p], aj[q], adot[p][q]);
            }
    }

#pragma unroll
    for (int p = 0; p < 4; ++p) {
        int li = ty + 16 * p;
        int ii = i0 + li;
        double rri = ri_[li], mmi = mi[li], ssi = si[li];
#pragma unroll
        for (int q = 0; q < 4; ++q) {
            int lj = tx + 16 * q;
            int jj = j0 + lj;
            double dot = adot[p][q];
            double d2  = rri + rj_[lj] - 2.0 * dot;
            double e   = (ii == jj) ? 0.0 : sqrt(fmax(d2, 0.0));
            double cc  = (dot - 64.0 * mmi * mj[lj]) * ssi * sj[lj];
            cc = fmin(1.0, fmax(-1.0, cc));
            size_t idx = (size_t)b * S + (size_t)ii * N + jj;
            E[idx]  = e;
            Ch[idx] = amax[p][q];
            Cc[idx] = cc;
        }
    }
}

// ---------------------------------------------------------------------------
// K2: C = scale * A * B^T (fp64, MFMA). 64x32 tile, 256 threads, 4 waves x
// (16x32); 1024 wgs -> 4 blocks/CU (verified 282.6us round). BK=16 dbuf.
__global__ __launch_bounds__(256, 4) void k_gemm_nt(const double* __restrict__ A,
                                                    const double* __restrict__ Bm,
                                                    double* __restrict__ Cm,
                                                    double scale,
                                                    unsigned int* __restrict__ bar,
                                                    unsigned int* __restrict__ ghist,
                                                    unsigned int* __restrict__ eqcnt,
                                                    unsigned long long* __restrict__ pubR) {
    if (blockIdx.x == 0 && blockIdx.y == 0 && blockIdx.z == 0) {
        int tt = threadIdx.x;
        for (int i = tt; i < 512; i += 256) bar[i] = 0u;
        for (int i = tt; i < 4 * 2 * 16 * 256; i += 256) ghist[i] = 0u;
        if (tt < 32) eqcnt[tt] = 0u;
        if (tt < 16) { pubR[tt] = 0ULL; }
    }

    int b = blockIdx.z;
    const double* Ab = A  + (size_t)b * S;
    const double* Bb = Bm + (size_t)b * S;
    double*       Cb = Cm + (size_t)b * S;
    int i0, j0;
    xcd_tile(i0, j0);    // i0: 64-row base, j0: 32-col base

    __shared__ double At[2][64][17];
    __shared__ double Bt[2][32][17];

    int t    = threadIdx.x;
    int lane = t & 63;
    int w    = t >> 6;            // 0..3, rows [w*16, w*16+16)
    int wrr  = w * 16;
    int fm   = lane & 15;
    int fk   = lane >> 4;

    int sa_r = t >> 2, sa_c = (t & 3) * 4;   // A: 64 rows x 16 k, 4 dbl/thr
    int sb_r = t >> 3, sb_c = (t & 7) * 2;   // B: 32 j-rows x 16 k, 2 dbl/thr

    d4 acc0 = {0.0, 0.0, 0.0, 0.0};
    d4 acc1 = acc0;

    const double* ap = Ab + (size_t)(i0 + sa_r) * N + sa_c;
    const double* bp = Bb + (size_t)(j0 + sb_r) * N + sb_c;

    double pa[4], pb[2];
#pragma unroll
    for (int m = 0; m < 4; ++m) pa[m] = ap[m];
#pragma unroll
    for (int m = 0; m < 2; ++m) pb[m] = bp[m];
#pragma unroll
    for (int m = 0; m < 4; ++m) At[0][sa_r][sa_c + m] = pa[m];
#pragma unroll
    for (int m = 0; m < 2; ++m) Bt[0][sb_r][sb_c + m] = pb[m];
    __syncthreads();

    int cur = 0;
    for (int k0 = 0; k0 < N; k0 += 16) {
        bool has_next = (k0 + 16 < N);
        if (has_next) {
            ap += 16; bp += 16;
#pragma unroll
            for (int m = 0; m < 4; ++m) pa[m] = ap[m];
#pragma unroll
            for (int m = 0; m < 2; ++m) pb[m] = bp[m];
        }
#pragma unroll
        for (int kq = 0; kq < 4; ++kq) {
            int kk = kq * 4 + fk;
            double a0 = At[cur][wrr + fm][kk];
            double b0 = Bt[cur][fm][kk];
            double b1 = Bt[cur][16 + fm][kk];
            acc0 = __builtin_amdgcn_mfma_f64_16x16x4f64(a0, b0, acc0, 0, 0, 0);
            acc1 = __builtin_amdgcn_mfma_f64_16x16x4f64(a0, b1, acc1, 0, 0, 0);
        }
        if (has_next) {
            int nxt = cur ^ 1;
#pragma unroll
            for (int m = 0; m < 4; ++m) At[nxt][sa_r][sa_c + m] = pa[m];
#pragma unroll
            for (int m = 0; m < 2; ++m) Bt[nxt][sb_r][sb_c + m] = pb[m];
            __syncthreads();
            cur = nxt;
        }
    }
    int r0 = i0 + wrr + 4 * fk;
    int c0 = j0 + fm;
#pragma unroll
    for (int r = 0; r < 4; ++r) {
        Cb[(size_t)(r0 + r) * N + c0]      = acc0[r] * scale;
        Cb[(size_t)(r0 + r) * N + c0 + 16] = acc1[r] * scale;
    }
}

// ---------------------------------------------------------------------------
// K4: W = A * B (fp64, MFMA) + key32 epilogue + pass-0 radix histogram.
__global__ __launch_bounds__(256, 4) void k_gemm_nn(const double* __restrict__ A,
                                                    const double* __restrict__ Bm,
                                                    double* __restrict__ Wm,
                                                    unsigned int* __restrict__ kq_out,
                                                    unsigned int* __restrict__ ghist) {
    int b = blockIdx.z;
    const double* Ab = A  + (size_t)b * S;
    const double* Bb = Bm + (size_t)b * S;
    double*       Wb = Wm + (size_t)b * S;
    unsigned int* kb = kq_out + (size_t)b * S;
    int i0, j0;
    xcd_tile(i0, j0);

    __shared__ double At[2][64][17];
    __shared__ double Bt[2][16][33];
    __shared__ int bh[256];

    int t    = threadIdx.x;
    int lane = t & 63;
    int w    = t >> 6;            // 0..3
    int wrr  = w * 16;
    int fm   = lane & 15;
    int fk   = lane >> 4;

    int sa_r = t >> 2, sa_c = (t & 3) * 4;    // A: 64 rows x 16 k
    int sb_r = t >> 4, sb_c = (t & 15) * 2;   // B: 16 k-rows x 32 cols

    d4 acc0 = {0.0, 0.0, 0.0, 0.0};
    d4 acc1 = acc0;

    const double* ap = Ab + (size_t)(i0 + sa_r) * N + sa_c;
    const double* bp = Bb + (size_t)sb_r * N + j0 + sb_c;

    double pa[4], pb[2];
#pragma unroll
    for (int m = 0; m < 4; ++m) pa[m] = ap[m];
#pragma unroll
    for (int m = 0; m < 2; ++m) pb[m] = bp[m];
#pragma unroll
    for (int m = 0; m < 4; ++m) At[0][sa_r][sa_c + m] = pa[m];
#pragma unroll
    for (int m = 0; m < 2; ++m) Bt[0][sb_r][sb_c + m] = pb[m];
    __syncthreads();

    int cur = 0;
    for (int k0 = 0; k0 < N; k0 += 16) {
        bool has_next = (k0 + 16 < N);
        if (has_next) {
            ap += 16; bp += (size_t)16 * N;
#pragma unroll
            for (int m = 0; m < 4; ++m) pa[m] = ap[m];
#pragma unroll
            for (int m = 0; m < 2; ++m) pb[m] = bp[m];
        }
#pragma unroll
        for (int kq = 0; kq < 4; ++kq) {
            int kk = kq * 4 + fk;
            double a0 = At[cur][wrr + fm][kk];
            double b0 = Bt[cur][kk][fm];
            double b1 = Bt[cur][kk][16 + fm];
            acc0 = __builtin_amdgcn_mfma_f64_16x16x4f64(a0, b0, acc0, 0, 0, 0);
            acc1 = __builtin_amdgcn_mfma_f64_16x16x4f64(a0, b1, acc1, 0, 0, 0);
        }
        if (has_next) {
            int nxt = cur ^ 1;
#pragma unroll
            for (int m = 0; m < 4; ++m) At[nxt][sa_r][sa_c + m] = pa[m];
#pragma unroll
            for (int m = 0; m < 2; ++m) Bt[nxt][sb_r][sb_c + m] = pb[m];
            __syncthreads();
            cur = nxt;
        }
    }
    int r0 = i0 + wrr + 4 * fk;
    int c0 = j0 + fm;

    unsigned int kreg[8];
#pragma unroll
    for (int r = 0; r < 4; ++r) {
        double w00 = acc0[r], w01 = acc1[r];
        size_t i00 = (size_t)(r0 + r) * N + c0;
        size_t i01 = (size_t)(r0 + r) * N + c0 + 16;
        unsigned int k00 = (unsigned int)(d2key(w00) >> 32);
        unsigned int k01 = (unsigned int)(d2key(w01) >> 32);
        Wb[i00] = w00; kb[i00] = k00;
        Wb[i01] = w01; kb[i01] = k01;
        kreg[2 * r + 0] = k00; kreg[2 * r + 1] = k01;
    }

    // pass-0 (top-byte) histogram of this block's 2048 outputs
    bh[t] = 0;
    __syncthreads();
#pragma unroll
    for (int m = 0; m < 8; ++m) atomicAdd(&bh[kreg[m] >> 24], 1);
    __syncthreads();
    if (bh[t] != 0)
        __hip_atomic_fetch_add(&ghist[((0 * 2 + b) * 16 + (blockIdx.x & 15)) * 256 + t],
                               (unsigned int)bh[t], __ATOMIC_RELAXED,
                               __HIP_MEMORY_SCOPE_AGENT);
}

// ---------------------------------------------------------------------------
// K3: fp64 row softmax. Wave per row, shuffle-only; 512 wgs.
__global__ __launch_bounds__(256) void k_softmax(double* __restrict__ L) {
    int row = (blockIdx.x << 2) + (threadIdx.x >> 6);
    int ln  = threadIdx.x & 63;
    double* p = L + (size_t)row * N;

    double v[16];
#pragma unroll
    for (int q = 0; q < 16; ++q) v[q] = p[ln + 64 * q];

    double mx = v[0];
#pragma unroll
    for (int q = 1; q < 16; ++q) mx = fmax(mx, v[q]);
#pragma unroll
    for (int off = 32; off >= 1; off >>= 1) mx = fmax(mx, __shfl_xor(mx, off));

    double s = 0.0;
#pragma unroll
    for (int q = 0; q < 16; ++q) { v[q] = exp(v[q] - mx); s += v[q]; }
#pragma unroll
    for (int off = 32; off >= 1; off >>= 1) s += __shfl_xor(s, off);

    double inv = 1.0 / s;
#pragma unroll
    for (int q = 0; q < 16; ++q) p[ln + 64 * q] = v[q] * inv;
}

// ---------------------------------------------------------------------------
// K5: fused selection v2 (verified: parallel pick256 scans, no stage-A
// publish round-trip, provisional mask overlapped with refine). v3's
// early-exit was measured +43us WORSE (serial leader refine over up to 16K
// candidates is latency-bound); reverted.
__global__ __launch_bounds__(256) void k_select(const unsigned int* __restrict__ key32,
                                                const double* __restrict__ W,
                                                unsigned int* __restrict__ ghist,
                                                unsigned int* __restrict__ eqcnt,
                                                unsigned long long* __restrict__ cand,
                                                unsigned long long* __restrict__ pubR,
                                                unsigned int* __restrict__ bar,
                                                float* __restrict__ out) {
    int blk = blockIdx.x, t = threadIdx.x;
    int b  = blk >> 7;            // 128 blocks per batch
    int lb = blk & 127;
    int lane = t & 63, wv = t >> 6;
    bool leader = (lb == 0);

    __shared__ int lh[256];
    __shared__ int wtot[4];
    __shared__ unsigned int wsum[4];
    __shared__ unsigned int sbase, s_tot, s_bk, s_ca;
    __shared__ unsigned long long s_pub;

    // XCD-aligned tile ownership: residue r8 = blk%8, two tiles per block.
    int r8 = blk & 7;
    int o  = lb >> 3;                       // 0..15
    int tf0 = r8 + 16 * o;
    int tf1 = tf0 + 8;
    int rr = t >> 2, c16 = (t & 3) * 16;
    int tb[2];
    tb[0] = ((tf0 >> 4) * 64 + rr) * N + (tf0 & 15) * 64 + c16;
    tb[1] = ((tf1 >> 4) * 64 + rr) * N + (tf1 & 15) * 64 + c16;

    const unsigned int* kb = key32 + (size_t)b * S;
    const double*       Wb = W     + (size_t)b * S;
    unsigned long long* myPubR = &pubR[b * 8];
    unsigned int* arr = bar + 64;   // arrival counters, 16-dword spacing

    unsigned int pref = 0, kneed = (unsigned int)KSEL;

    // ---- stage A: 4 radix passes; pass 0's hist came from K4's epilogue ----
    for (int p = 0; p < 4; ++p) {
        int shift = 24 - 8 * p;
        if (p > 0) {
            lh[t] = 0;
            __syncthreads();
#pragma unroll
            for (int u = 0; u < 2; ++u)
#pragma unroll
                for (int m4 = 0; m4 < 4; ++m4) {
                    uint4 kv = *(const uint4*)(kb + tb[u] + 4 * m4);
                    unsigned int ks[4] = {kv.x, kv.y, kv.z, kv.w};
#pragma unroll
                    for (int c = 0; c < 4; ++c) {
                        bool match = (((unsigned long long)(ks[c] ^ pref)) >> (shift + 8)) == 0ULL;
                        if (match) atomicAdd(&lh[(ks[c] >> shift) & 255u], 1);
                    }
                }
            __syncthreads();
            if (lh[t] != 0)
                __hip_atomic_fetch_add(&ghist[((p * 2 + b) * 16 + (lb >> 3)) * 256 + t],
                                       (unsigned int)lh[t], __ATOMIC_RELAXED,
                                       __HIP_MEMORY_SCOPE_AGENT);
            // drain hist RMWs, arrive, wait for all 128 arrivals (no publish)
            asm volatile("s_waitcnt vmcnt(0)" ::: "memory");
            __syncthreads();
            if (t == 0) {
                unsigned int* slot = &arr[((p - 1) * 2 + b) * 16];
                __hip_atomic_fetch_add(slot, 1u, __ATOMIC_RELAXED,
                                       __HIP_MEMORY_SCOPE_AGENT);
                while (aload(slot) < 128u) __builtin_amdgcn_s_sleep(4);
            }
            __syncthreads();
        }
        // every block: sum the 16 group hists for its bucket, pick locally
        unsigned int c = 0;
#pragma unroll
        for (int g = 0; g < 16; ++g)
            c += aload(&ghist[((p * 2 + b) * 16 + g) * 256 + t]);
        pick256(c, kneed, t, wsum, &s_bk, &s_ca);
        pref |= (s_bk << shift);
        kneed -= s_ca;
    }

    // ---- collect exact ties (key32 == pref): block-aggregated counter ----
    unsigned long long lmask = (1ULL << lane) - 1ULL;
    unsigned long long* cb = cand + (size_t)b * EQCAP;
    {
        int wcnt = 0;
#pragma unroll
        for (int u = 0; u < 2; ++u)
#pragma unroll
            for (int m4 = 0; m4 < 4; ++m4) {
                uint4 kv = *(const uint4*)(kb + tb[u] + 4 * m4);
                unsigned int ks[4] = {kv.x, kv.y, kv.z, kv.w};
#pragma unroll
                for (int c = 0; c < 4; ++c) {
                    unsigned long long mb = __ballot(ks[c] == pref);
                    wcnt += (int)__popcll(mb);
                }
            }
        if (lane == 0) wtot[wv] = wcnt;
        __syncthreads();
        if (t == 0) {
            int tot = wtot[0] + wtot[1] + wtot[2] + wtot[3];
            s_tot = (unsigned int)tot;
            sbase = (tot > 0)
                ? __hip_atomic_fetch_add(&eqcnt[b * 16], (unsigned int)tot,
                                         __ATOMIC_RELAXED, __HIP_MEMORY_SCOPE_AGENT)
                : 0u;
        }
        __syncthreads();
        unsigned int wb2 = sbase;
        for (int w2 = 0; w2 < wv; ++w2) wb2 += (unsigned int)wtot[w2];
#pragma unroll
        for (int u = 0; u < 2; ++u)
#pragma unroll
            for (int m4 = 0; m4 < 4; ++m4) {
                uint4 kv = *(const uint4*)(kb + tb[u] + 4 * m4);
                unsigned int ks[4] = {kv.x, kv.y, kv.z, kv.w};
#pragma unroll
                for (int c = 0; c < 4; ++c) {
                    bool m = (ks[c] == pref);
                    unsigned long long mb = __ballot(m);
                    if (m) {
                        unsigned int pos = wb2 + (unsigned int)__popcll(mb & lmask);
                        if (pos < (unsigned int)EQCAP) {
                            int s = tb[u] + 4 * m4 + c;
                            unsigned int low = (unsigned int)d2key(Wb[s]);
                            astore64(&cb[pos],
                                     (((unsigned long long)(unsigned int)s) << 32) | low);
                        }
                    }
                    wb2 += (unsigned int)__popcll(mb);
                }
            }
    }
    // drain cand/eqcnt RMWs, announce tie arrival (slot 6+b)
    asm volatile("s_waitcnt vmcnt(0)" ::: "memory");
    __syncthreads();
    if (t == 0)
        __hip_atomic_fetch_add(&arr[(6 + b) * 16], 1u,
                               __ATOMIC_RELAXED, __HIP_MEMORY_SCOPE_AGENT);
    unsigned int tot = s_tot;

    // ---- M1: provisional mask (ties -> 0), overlaps the refine below ----
    float4* ob = (float4*)(out + (size_t)b * S);
#pragma unroll
    for (int u = 0; u < 2; ++u)
#pragma unroll
        for (int m4 = 0; m4 < 4; ++m4) {
            uint4 kv = *(const uint4*)(kb + tb[u] + 4 * m4);
            unsigned int ks[4] = {kv.x, kv.y, kv.z, kv.w};
            float4 ov;
            ov.x = (ks[0] > pref) ? 1.0f : 0.0f;
            ov.y = (ks[1] > pref) ? 1.0f : 0.0f;
            ov.z = (ks[2] > pref) ? 1.0f : 0.0f;
            ov.w = (ks[3] > pref) ? 1.0f : 0.0f;
            ob[(tb[u] >> 2) + m4] = ov;
        }

    // ---- refine (leader block per batch): 4 passes low32 + 3 passes idx ----
    if (leader) {
        if (t == 0)
            while (aload(&arr[(6 + b) * 16]) < 128u) __builtin_amdgcn_s_sleep(4);
        __syncthreads();
        unsigned int cnt = aload(&eqcnt[b * 16]);
        if (cnt > (unsigned int)EQCAP) cnt = EQCAP;
        unsigned int rpref = 0, rkneed = kneed;
        for (int shift = 24; shift >= 0; shift -= 8) {
            lh[t] = 0;
            __syncthreads();
            for (unsigned int e = t; e < cnt; e += 256) {
                unsigned int low = (unsigned int)aload64(&cb[e]);
                if ((((unsigned long long)(low ^ rpref)) >> (shift + 8)) == 0ULL)
                    atomicAdd(&lh[(low >> shift) & 255u], 1);
            }
            __syncthreads();
            pick256((unsigned int)lh[t], rkneed, t, wsum, &s_bk, &s_ca);
            rpref |= (s_bk << shift);
            rkneed -= s_ca;
        }
        unsigned int TL = rpref;
        unsigned int ipref = 0;
        for (int shift = 16; shift >= 0; shift -= 8) {
            lh[t] = 0;
            __syncthreads();
            for (unsigned int e = t; e < cnt; e += 256) {
                unsigned long long pr = aload64(&cb[e]);
                if ((unsigned int)pr != TL) continue;
                unsigned int idx = (unsigned int)(pr >> 32);
                if ((((unsigned long long)(idx ^ ipref)) >> (shift + 8)) == 0ULL)
                    atomicAdd(&lh[(idx >> shift) & 255u], 1);
            }
            __syncthreads();
            pick256((unsigned int)lh[t], rkneed, t, wsum, &s_bk, &s_ca);
            ipref |= (s_bk << shift);
            rkneed -= s_ca;
        }
        if (t == 0)
            astore64(myPubR, (1ULL << 56) | (((unsigned long long)TL) << 20) |
                             (unsigned long long)ipref);
    } else if (tot == 0) {
        return;   // mask fully final for this block; no tie fixup needed
    }
    if (tot == 0) return;   // leader with no local ties: published, done

    // ---- tie holders: poll refine publish, fix up equal entries ----
    if (t == 0) {
        unsigned long long v;
        while (((v = aload64(myPubR)) >> 56) != 1ULL) __builtin_amdgcn_s_sleep(4);
        s_pub = v;
    }
    __syncthreads();
    unsigned long long vR = s_pub;
    unsigned int TL   = (unsigned int)((vR >> 20) & 0xFFFFFFFFULL);
    unsigned int sCut = (unsigned int)(vR & 0xFFFFFULL);

    asm volatile("s_waitcnt vmcnt(0)" ::: "memory");   // M1 stores drained
    float* of = out + (size_t)b * S;
#pragma unroll
    for (int u = 0; u < 2; ++u)
#pragma unroll
        for (int m4 = 0; m4 < 4; ++m4) {
            uint4 kv = *(const uint4*)(kb + tb[u] + 4 * m4);
            unsigned int ks[4] = {kv.x, kv.y, kv.z, kv.w};
#pragma unroll
            for (int c = 0; c < 4; ++c) {
                if (ks[c] == pref) {
                    int s = tb[u] + 4 * m4 + c;
                    unsigned int low = (unsigned int)d2key(Wb[s]);
                    of[s] = (low > TL || (low == TL && (unsigned int)s >= sCut))
                                ? 1.0f : 0.0f;
                }
            }
        }
}

// ---------------------------------------------------------------------------
extern "C" void kernel_launch(void* const* d_in, const int* in_sizes, int n_in,
                              void* d_out, int out_size, void* d_ws, size_t ws_size,
                              hipStream_t stream) {
    const float* x = (const float*)d_in[0];
    float* out = (float*)d_out;

    char* ws = (char*)d_ws;
    size_t off = 0;
    auto alloc = [&](size_t bytes) -> void* {
        void* p = ws + off;
        off += (bytes + 255) & ~(size_t)255;
        return p;
    };

    double* E     = (double*)alloc((size_t)BB * S * sizeof(double));       // 16 MB
    double* Ch    = (double*)alloc((size_t)BB * S * sizeof(double));       // 16 MB
    double* Cc    = (double*)alloc((size_t)BB * S * sizeof(double));       // 16 MB
    double* L     = (double*)alloc((size_t)BB * S * sizeof(double));       // 16 MB
    unsigned int* key32 = (unsigned int*)alloc((size_t)BB * S * sizeof(unsigned int)); // 8 MB
    double* W     = E;  // E dead after gemm_nt -> reuse for weighted
    unsigned int* bar   = (unsigned int*)alloc(2048);
    unsigned int* ghist = (unsigned int*)alloc(4 * 2 * 16 * 256 * sizeof(unsigned int)); // 128 KB
    unsigned int* eqcnt = (unsigned int*)alloc(BB * 64);
    unsigned long long* cand =
        (unsigned long long*)alloc((size_t)BB * EQCAP * sizeof(unsigned long long));     // 2 MB
    unsigned long long* pubR = (unsigned long long*)alloc(128);

    // 1) pairwise adjacencies (fused per-row stats)
    k_pairwise<<<dim3(N / 64, N / 64, BB), 256, 0, stream>>>(x, E, Ch, Cc);

    // 2) logits = (E @ Ch^T) * 1/8, 64x32 tiles (+ zeroes select scratch)
    k_gemm_nt<<<dim3(N / 32, N / 64, BB), 256, 0, stream>>>(E, Ch, L, 0.125,
                                                            bar, ghist, eqcnt, pubR);

    // 3) softmax rows
    k_softmax<<<512, 256, 0, stream>>>(L);

    // 4) weighted = attn @ Cc, 64x32 tiles + key32 epilogue + pass-0 histogram
    k_gemm_nn<<<dim3(N / 32, N / 64, BB), 256, 0, stream>>>(L, Cc, W, key32, ghist);

    // 5) fused selection v2 (parallel scans, no stage-A publish, overlapped mask)
    k_select<<<NSELBLK, 256, 0, stream>>>(key32, W, ghist, eqcnt, cand, pubR, bar, out);
}